// Round 9
// baseline (251.234 us; speedup 1.0000x reference)
//
#include <hip/hip_runtime.h>
#include <hip/hip_bf16.h>
#include <hip/hip_fp16.h>

// GCN 2-layer: h1 = relu(A_hat (x@W1) + b1); out = log_softmax(A_hat (h1@W2) + b2)
// R21 = R20 with the bcur init RACE fixed (R20 core-dumped: staging block init of
// bcur[t]=t*STG raced with scatter blocks' atomicAdd allocation -> garbage offsets
// -> OOB). Now bcur holds pure COUNTS, zero-init by extending the deg memset
// (adjacent in ws); scatter computes slice = t*STG + atomicAdd(&bcur[t], h[t]).
// Order-independent (Guideline 16). Rest = R20:
//  (a) deg[] atomics folded into k_bscatter -> k_cg fuses csr build (blocks [0,nb))
//      with MFMA gemm1 (blocks [nb,..), 128 rows/block, dn=rsqrtf(deg+1) inline,
//      writes dis; h1 PRE-SCALED).
//  (b) agg1f 4 row-loads in flight (halves exposed L2 latency at deg~16).
// fp32 accumulation everywhere (order-insensitive).

#define F1 64
#define F2 16
#define NBKT 256  // bucket bin array size (nb = 196)
#define BSH 512   // nodes per bucket; bucket = dst>>9, local = dst&511
#define NPB 256   // scatter blocks
#define SBD 1024  // scatter block dim
#define STG 9216  // bucket region stride (mean 8192, sigma ~90)

typedef _Float16 f16x8 __attribute__((ext_vector_type(8)));
typedef _Float16 f16x4 __attribute__((ext_vector_type(4)));
typedef float f32x2 __attribute__((ext_vector_type(2)));
typedef float f32x4 __attribute__((ext_vector_type(4)));
typedef float f32x8 __attribute__((ext_vector_type(8)));

__device__ inline f32x8 shfl_xor_f32x8(f32x8 v, int off) {
  f32x8 r;
#pragma unroll
  for (int k = 0; k < 8; ++k) r[k] = __shfl_xor(v[k], off);
  return r;
}
__device__ inline f32x4 shfl_xor_f32x4(f32x4 v, int off) {
  f32x4 r;
#pragma unroll
  for (int k = 0; k < 4; ++k) r[k] = __shfl_xor(v[k], off);
  return r;
}

// accumulate 8 fp8 (e4m3) features into 4 f32x2 accs via packed cvt + packed add
__device__ inline void acc_fp8x8(f32x2* a, uint2 v) {
  a[0] += __builtin_amdgcn_cvt_pk_f32_fp8((int)v.x, false);
  a[1] += __builtin_amdgcn_cvt_pk_f32_fp8((int)v.x, true);
  a[2] += __builtin_amdgcn_cvt_pk_f32_fp8((int)v.y, false);
  a[3] += __builtin_amdgcn_cvt_pk_f32_fp8((int)v.y, true);
}

// ---- 1) bucket scatter + deg atomics; extra block stages weights ----
// bcur[] holds per-bucket COUNTS (zero-init by host memset); slice base = t*STG + old.
__global__ void k_bscatter(const int* __restrict__ src, const int* __restrict__ dst,
                           int* __restrict__ bcur, int* __restrict__ tmp,
                           int* __restrict__ deg, int E, int nb, int chunk,
                           const float* __restrict__ W1, const float* __restrict__ W2,
                           const float* __restrict__ b1,
                           __half* __restrict__ W1T, __half* __restrict__ W2Tp,
                           float* __restrict__ b1p) {
  int t = threadIdx.x, sb = blockIdx.x;
  if (sb == NPB) {  // weight staging block (no shared state with scatter blocks)
    for (int i = t; i < 64 * 64; i += SBD) {
      int n = i >> 6, k = i & 63;
      W1T[i] = __float2half(W1[k * 64 + n]);
    }
    // W2Tp[j*64 + p] = W2[f(p)][j], f(p) = 16*(p&3) + (p>>2)  (gemm1's permuted order)
    for (int i = t; i < 16 * 64; i += SBD) {
      int j = i >> 6, p = i & 63;
      int fp = 16 * (p & 3) + (p >> 2);
      W2Tp[i] = __float2half(W2[fp * 16 + j]);
    }
    if (t < 64) b1p[t] = b1[16 * (t & 3) + (t >> 2)];
    return;
  }
  __shared__ int h[NBKT];
  __shared__ int cur[NBKT];
  int beg = sb * chunk, end = min(beg + chunk, E);
  if (t < NBKT) h[t] = 0;
  __syncthreads();
  int e;
  for (e = beg + t * 4; e + 4 <= end; e += 4 * SBD) {
    int4 d4 = *(const int4*)(dst + e);
    atomicAdd(&h[d4.x >> 9], 1);
    atomicAdd(&h[d4.y >> 9], 1);
    atomicAdd(&h[d4.z >> 9], 1);
    atomicAdd(&h[d4.w >> 9], 1);
    atomicAdd(&deg[d4.x], 1);
    atomicAdd(&deg[d4.y], 1);
    atomicAdd(&deg[d4.z], 1);
    atomicAdd(&deg[d4.w], 1);
  }
  for (; e < end; ++e) {
    int d = dst[e];
    atomicAdd(&h[d >> 9], 1);
    atomicAdd(&deg[d], 1);
  }
  __syncthreads();
  // allocate this block's contiguous slice in each bucket region (count-based,
  // order-independent: bcur zero-init by memset, base = t*STG + prior count)
  if (t < nb) cur[t] = t * STG + atomicAdd(&bcur[t], h[t]);
  __syncthreads();
  // place packed edges at global positions (chunk is L2-hot from pass 1)
  for (e = beg + t * 4; e + 4 <= end; e += 4 * SBD) {
    int4 d4 = *(const int4*)(dst + e);
    int4 s4 = *(const int4*)(src + e);
    int b, off;
    b = d4.x >> 9; off = atomicAdd(&cur[b], 1); tmp[off] = (s4.x << 9) | (d4.x & 511);
    b = d4.y >> 9; off = atomicAdd(&cur[b], 1); tmp[off] = (s4.y << 9) | (d4.y & 511);
    b = d4.z >> 9; off = atomicAdd(&cur[b], 1); tmp[off] = (s4.z << 9) | (d4.z & 511);
    b = d4.w >> 9; off = atomicAdd(&cur[b], 1); tmp[off] = (s4.w << 9) | (d4.w & 511);
  }
  for (; e < end; ++e) {
    int d = dst[e];
    int b = d >> 9;
    int off = atomicAdd(&cur[b], 1);
    tmp[off] = (src[e] << 9) | (d & 511);
  }
}

// ---- 2) FUSED: blocks [0,nb) = csr build; blocks [nb,..) = MFMA gemm1 ----
// csr role: coalesced bucket staging -> LDS count/scan/place -> csr + rowptr.
// gemm role: h1[n] = fp8_perm(dn * (x[n] @ W1)), dn = rsqrtf(deg[n]+1); writes dis.
__global__ void k_cg(const int* __restrict__ tmp, const int* __restrict__ bcur,
                     int* __restrict__ csr, int* __restrict__ rowptr,
                     const float* __restrict__ x, const __half* __restrict__ W1T,
                     const int* __restrict__ deg, float* __restrict__ dis,
                     unsigned char* __restrict__ h1, int N, int nb) {
  __shared__ int stage[STG];
  __shared__ int sc[BSH];
  __shared__ int cnt[BSH];
  __shared__ int lofs[BSH];
  int b = blockIdx.x, t = threadIdx.x;  // 512 threads
  if (b >= nb) {
    // ---- gemm1 role: 128 rows per block (8 waves x 16 rows) ----
    int g = b - nb;
    int wv = t >> 6, lane = t & 63;
    int m = lane & 15, q = lane >> 4;  // quad
    int row0 = g * 128 + wv * 16;
    int arow = min(row0 + m, N - 1);  // clamp for load safety
    const _Float16* wt = (const _Float16*)W1T;
    f16x8 bf[4][2];
#pragma unroll
    for (int c = 0; c < 4; ++c)
#pragma unroll
      for (int kt = 0; kt < 2; ++kt)
        bf[c][kt] = *(const f16x8*)&wt[(c * 16 + m) * 64 + kt * 32 + q * 8];
    f16x8 a[2];
#pragma unroll
    for (int kt = 0; kt < 2; ++kt) {
      const float4* xp = (const float4*)(x + (size_t)arow * 64 + kt * 32 + q * 8);
      float4 u = xp[0], v = xp[1];
      a[kt][0] = (_Float16)u.x; a[kt][1] = (_Float16)u.y;
      a[kt][2] = (_Float16)u.z; a[kt][3] = (_Float16)u.w;
      a[kt][4] = (_Float16)v.x; a[kt][5] = (_Float16)v.y;
      a[kt][6] = (_Float16)v.z; a[kt][7] = (_Float16)v.w;
    }
    f32x4 acc[4] = {};
#pragma unroll
    for (int kt = 0; kt < 2; ++kt)
#pragma unroll
      for (int c = 0; c < 4; ++c)
        acc[c] = __builtin_amdgcn_mfma_f32_16x16x32_f16(a[kt], bf[c][kt], acc[c], 0, 0, 0);
#pragma unroll
    for (int r = 0; r < 4; ++r) {
      int n = row0 + q * 4 + r;
      if (n < N) {
        float dn = rsqrtf((float)(deg[n] + 1));
        if (m == 0) dis[n] = dn;
        int d = __builtin_amdgcn_cvt_pk_fp8_f32(acc[0][r] * dn, acc[1][r] * dn, 0, false);
        d = __builtin_amdgcn_cvt_pk_fp8_f32(acc[2][r] * dn, acc[3][r] * dn, d, true);
        *(unsigned int*)(h1 + (size_t)n * 64 + m * 4) = (unsigned)d;
      }
    }
    return;
  }
  // ---- csr role ----
  int lenb = bcur[b];  // bucket count
  // csr base of bucket b = prefix sum of bucket counts (256-wide scan)
  if (t < NBKT) sc[t] = (t < nb) ? bcur[t] : 0;
  __syncthreads();
  for (int off = 1; off < NBKT; off <<= 1) {
    int a = (t < NBKT && t >= off) ? sc[t - off] : 0;
    __syncthreads();
    if (t < NBKT) sc[t] += a;
    __syncthreads();
  }
  int beg = (b == 0) ? 0 : sc[b - 1];
  __syncthreads();
  // stage bucket region into LDS: contiguous, coalesced int4
  int s0 = b * STG;
  int lim = lenb & ~3;
  for (int i = t * 4; i < lim; i += 4 * BSH)
    *(int4*)(stage + i) = *(const int4*)(tmp + s0 + i);
  {
    int r = lim + t;
    if (r < lenb) stage[r] = tmp[s0 + r];
  }
  cnt[t] = 0;
  __syncthreads();
  for (int i = t; i < lenb; i += BSH) atomicAdd(&cnt[stage[i] & (BSH - 1)], 1);
  __syncthreads();
  sc[t] = cnt[t];
  __syncthreads();
  for (int off = 1; off < BSH; off <<= 1) {
    int a = (t >= off) ? sc[t - off] : 0;
    __syncthreads();
    sc[t] += a;
    __syncthreads();
  }
  int excl = (t == 0) ? 0 : sc[t - 1];
  lofs[t] = excl;
  int n = b * BSH + t;
  if (n <= N) rowptr[n] = beg + excl;  // n==N lands on E
  cnt[t] = 0;  // reuse as cursor
  __syncthreads();
  for (int i = t; i < lenb; i += BSH) {
    int p = stage[i];
    int l = p & (BSH - 1);
    int off = atomicAdd(&cnt[l], 1);
    csr[beg + lofs[l] + off] = p >> 9;
  }
}

// ---- agg layer 1 + fused GEMM2: 2 nodes/wave (half=32 lanes: 4 subs x 8 fl) ----
// h1 rows are 64 B fp8 (permuted feature order, pre-scaled by dis); fp32 accumulate.
// 4 row-loads in flight per iteration (halves exposed L2 latency at deg~16).
__global__ void k_agg1f(const unsigned char* __restrict__ h, const float* __restrict__ dis,
                        const int* __restrict__ rowptr, const int* __restrict__ csr,
                        const float* __restrict__ b1p, const __half* __restrict__ W2Tp,
                        __half* __restrict__ h2, int N) {
  int gt = blockIdx.x * blockDim.x + threadIdx.x;
  int w = gt >> 6;
  int lane = gt & 63;
  int half = lane >> 5;         // node within wave
  int sub = (lane >> 3) & 3;    // 4 edge substreams per node
  int fl = lane & 7;            // feature-octet lane
  int n = w * 2 + half;
  if (n >= N) return;
  float dn = dis[n];
  float4 bu = *(const float4*)(b1p + fl * 8);
  float4 bv = *(const float4*)(b1p + fl * 8 + 4);
  const _Float16* wt = (const _Float16*)W2Tp;
  // 4 outputs per sub: j = sub*4 + i
  f16x8 wj[4];
#pragma unroll
  for (int i = 0; i < 4; ++i)
    wj[i] = *(const f16x8*)&wt[(sub * 4 + i) * 64 + fl * 8];
  f32x2 a0[4] = {}, a1[4] = {};
  if (sub == 0)  // self loop (rows pre-scaled by dis)
    acc_fp8x8(a0, *(const uint2*)&h[(size_t)n * 64 + fl * 8]);
  int beg = rowptr[n], end = rowptr[n + 1];
  int e = beg + sub;
  int s0 = (e < end) ? csr[e] : -1;
  int s1 = (e + 4 < end) ? csr[e + 4] : -1;
  int s2 = (e + 8 < end) ? csr[e + 8] : -1;
  int s3 = (e + 12 < end) ? csr[e + 12] : -1;
  while (s3 >= 0) {
    int e2 = e + 16;
    int t0 = (e2 < end) ? csr[e2] : -1;
    int t1 = (e2 + 4 < end) ? csr[e2 + 4] : -1;
    int t2 = (e2 + 8 < end) ? csr[e2 + 8] : -1;
    int t3 = (e2 + 12 < end) ? csr[e2 + 12] : -1;
    uint2 v0 = *(const uint2*)&h[(size_t)s0 * 64 + fl * 8];
    uint2 v1 = *(const uint2*)&h[(size_t)s1 * 64 + fl * 8];
    uint2 v2 = *(const uint2*)&h[(size_t)s2 * 64 + fl * 8];
    uint2 v3 = *(const uint2*)&h[(size_t)s3 * 64 + fl * 8];
    acc_fp8x8(a0, v0);
    acc_fp8x8(a1, v1);
    acc_fp8x8(a0, v2);
    acc_fp8x8(a1, v3);
    s0 = t0; s1 = t1; s2 = t2; s3 = t3; e = e2;
  }
  // tail: up to 3 remaining streams (independent loads)
  if (s0 >= 0) acc_fp8x8(a0, *(const uint2*)&h[(size_t)s0 * 64 + fl * 8]);
  if (s1 >= 0) acc_fp8x8(a1, *(const uint2*)&h[(size_t)s1 * 64 + fl * 8]);
  if (s2 >= 0) acc_fp8x8(a0, *(const uint2*)&h[(size_t)s2 * 64 + fl * 8]);
  f32x8 acc;
#pragma unroll
  for (int k = 0; k < 4; ++k) {
    f32x2 s = a0[k] + a1[k];
    acc[2 * k] = s[0];
    acc[2 * k + 1] = s[1];
  }
  // reduce across the 4 substreams (stay within 32-lane half), fp32
  acc += shfl_xor_f32x8(acc, 8);
  acc += shfl_xor_f32x8(acc, 16);
  // bias + relu in fp32
  float bb[8] = {bu.x, bu.y, bu.z, bu.w, bv.x, bv.y, bv.z, bv.w};
  float hr[8];
#pragma unroll
  for (int k = 0; k < 8; ++k)
    hr[k] = fmaxf(fmaf(dn, acc[k], bb[k]), 0.f);
  // fused gemm2 in fp32: outputs j = sub*4 .. sub*4+3
  float p[4];
#pragma unroll
  for (int i = 0; i < 4; ++i) {
    float s = 0.f;
#pragma unroll
    for (int k = 0; k < 8; ++k) s = fmaf(hr[k], (float)wj[i][k], s);
    s += __shfl_xor(s, 1);
    s += __shfl_xor(s, 2);
    s += __shfl_xor(s, 4);
    p[i] = s;
  }
  if (fl == 0) {
    f16x4 o;
#pragma unroll
    for (int i = 0; i < 4; ++i) o[i] = (_Float16)(p[i] * dn);
    *(f16x4*)((_Float16*)h2 + (size_t)n * 16 + sub * 4) = o;
  }
}

// ---- agg layer 2 + bias + log_softmax: 2 nodes/wave (8 subs x 4 fl per node) ----
__global__ void k_agg2(const __half* __restrict__ h2, const float* __restrict__ dis,
                       const int* __restrict__ rowptr, const int* __restrict__ csr,
                       const float* __restrict__ b2, float* __restrict__ out, int N) {
  int gt = blockIdx.x * blockDim.x + threadIdx.x;
  int w = gt >> 6;
  int lane = gt & 63;
  int half = lane >> 5;
  int sub = (lane >> 2) & 7;  // 8 edge substreams per node
  int fl = lane & 3;          // feature-quad lane
  int n = w * 2 + half;
  if (n >= N) return;
  const _Float16* hp = (const _Float16*)h2;
  f32x4 acc0 = {}, acc1 = {};
  if (sub == 0)  // self loop (h2 rows pre-scaled by dis)
    acc0 = __builtin_convertvector(*(const f16x4*)&hp[(size_t)n * 16 + fl * 4], f32x4);
  int beg = rowptr[n], end = rowptr[n + 1];
  int e = beg + sub;
  int sA = (e < end) ? csr[e] : -1;
  int sB = (e + 8 < end) ? csr[e + 8] : -1;
  while (sB >= 0) {
    int e2 = e + 16;
    int sC = (e2 < end) ? csr[e2] : -1;
    int sD = (e2 + 8 < end) ? csr[e2 + 8] : -1;
    f16x4 v0 = *(const f16x4*)&hp[(size_t)sA * 16 + fl * 4];
    f16x4 v1 = *(const f16x4*)&hp[(size_t)sB * 16 + fl * 4];
    acc0 += __builtin_convertvector(v0, f32x4);
    acc1 += __builtin_convertvector(v1, f32x4);
    sA = sC; sB = sD; e = e2;
  }
  if (sA >= 0)
    acc0 += __builtin_convertvector(*(const f16x4*)&hp[(size_t)sA * 16 + fl * 4], f32x4);
  f32x4 acc = acc0 + acc1;
  // reduce across 8 substreams (within half), fp32
  acc += shfl_xor_f32x4(acc, 4);
  acc += shfl_xor_f32x4(acc, 8);
  acc += shfl_xor_f32x4(acc, 16);
  if (sub == 0) {
    float dn = dis[n];
    float4 bb = *(const float4*)(b2 + fl * 4);
    float v0 = fmaf(dn, acc[0], bb.x);
    float v1 = fmaf(dn, acc[1], bb.y);
    float v2 = fmaf(dn, acc[2], bb.z);
    float v3 = fmaf(dn, acc[3], bb.w);
    float m = fmaxf(fmaxf(v0, v1), fmaxf(v2, v3));
    m = fmaxf(m, __shfl_xor(m, 1));
    m = fmaxf(m, __shfl_xor(m, 2));
    float s2 = __expf(v0 - m) + __expf(v1 - m) + __expf(v2 - m) + __expf(v3 - m);
    s2 += __shfl_xor(s2, 1);
    s2 += __shfl_xor(s2, 2);
    float ls = m + __logf(s2);
    float4 o = {v0 - ls, v1 - ls, v2 - ls, v3 - ls};
    *(float4*)(out + (size_t)n * 16 + fl * 4) = o;
  }
}

extern "C" void kernel_launch(void* const* d_in, const int* in_sizes, int n_in,
                              void* d_out, int out_size, void* d_ws, size_t ws_size,
                              hipStream_t stream) {
  const float* x = (const float*)d_in[0];
  const int* ei = (const int*)d_in[1];
  const float* W1 = (const float*)d_in[2];
  const float* b1 = (const float*)d_in[3];
  const float* W2 = (const float*)d_in[4];
  const float* b2 = (const float*)d_in[5];
  float* out = (float*)d_out;

  int N = in_sizes[0] / F1;  // 100000
  int E = in_sizes[1] / 2;   // 1600000
  const int* src = ei;
  const int* dst = ei + E;
  int nb = (N + BSH - 1) >> 9;  // 196 buckets
  int chunk = ((E + NPB - 1) / NPB + 3) & ~3;  // 6252

  char* ws = (char*)d_ws;
  size_t o_w1t = 0;                                                   // 64*64 fp16
  size_t o_w2t = o_w1t + 64 * 64 * 2;                                 // 16*64 fp16
  size_t o_b1p = (o_w2t + 16 * 64 * 2 + 255) & ~(size_t)255;          // 64 f32
  size_t o_bcur = (o_b1p + 64 * 4 + 255) & ~(size_t)255;              // NBKT int (counts)
  size_t o_deg = (o_bcur + NBKT * 4 + 255) & ~(size_t)255;            // N int
  size_t o_dis = (o_deg + (size_t)N * 4 + 255) & ~(size_t)255;        // N f32
  size_t o_rowp = (o_dis + (size_t)N * 4 + 255) & ~(size_t)255;       // N+1 int
  size_t o_tmp = (o_rowp + (size_t)(N + 1) * 4 + 255) & ~(size_t)255; // nb*STG int
  size_t o_csr = (o_tmp + (size_t)nb * STG * 4 + 255) & ~(size_t)255; // E int
  size_t o_h1 = (o_csr + (size_t)E * 4 + 255) & ~(size_t)255;         // N*64 fp8
  size_t o_h2 = (o_h1 + (size_t)N * 64 + 255) & ~(size_t)255;         // N*16 fp16

  __half* W1T = (__half*)(ws + o_w1t);
  __half* W2Tp = (__half*)(ws + o_w2t);
  float* b1p = (float*)(ws + o_b1p);
  int* bcur = (int*)(ws + o_bcur);
  int* deg = (int*)(ws + o_deg);
  float* dis = (float*)(ws + o_dis);
  int* rowptr = (int*)(ws + o_rowp);
  int* tmp = (int*)(ws + o_tmp);
  int* csr = (int*)(ws + o_csr);
  unsigned char* h1 = (unsigned char*)(ws + o_h1);
  __half* h2 = (__half*)(ws + o_h2);

  // zero bcur (counts) + deg in one memset (adjacent regions)
  hipMemsetAsync(bcur, 0, (o_deg - o_bcur) + (size_t)N * 4, stream);
  k_bscatter<<<NPB + 1, SBD, 0, stream>>>(src, dst, bcur, tmp, deg, E, nb, chunk,
                                          W1, W2, b1, W1T, W2Tp, b1p);
  int gb2 = (N + 127) / 128;  // 782 gemm blocks
  k_cg<<<nb + gb2, BSH, 0, stream>>>(tmp, bcur, csr, rowptr, x, W1T, deg, dis,
                                     h1, N, nb);
  int aw = (N + 1) / 2;  // waves for 2-node-per-wave agg kernels
  k_agg1f<<<((size_t)aw * 64 + 255) / 256, 256, 0, stream>>>(h1, dis, rowptr, csr, b1p, W2Tp, h2, N);
  k_agg2<<<((size_t)aw * 64 + 255) / 256, 256, 0, stream>>>(h2, dis, rowptr, csr, b2, out, N);
}

// Round 10
// 200.472 us; speedup vs baseline: 1.2532x; 1.2532x over previous
//
#include <hip/hip_runtime.h>
#include <hip/hip_bf16.h>
#include <hip/hip_fp16.h>

// GCN 2-layer: h1 = relu(A_hat (x@W1) + b1); out = log_softmax(A_hat (h1@W2) + b2)
// R22 = R19 (proven 181-184us pipeline) + ONE change: 4 gather-loads in flight in
// both agg kernels (was 2). R21 measured the R20 ideas as regressions: 1.6M global
// deg atomics cost ~+35us in bscatter (device-scope RMW at memory-side cache,
// ~16-way contention) -- dropped; csr|gemm fusion dropped with it (gemm needs dis,
// dis needs k_csr). dis comes from k_csr's exact per-node counts as in R19.
// Pipeline: k_w (weights+bcur init) -> k_bscatter (bucket regions) -> k_csr
// (coalesced bucket staging -> csr/rowptr/dis) -> k_gemm1 (MFMA, permuted fp8 h1,
// pre-scaled) -> k_agg1f (fp8 gather + fused gemm2) -> k_agg2 (+ log_softmax).
// fp32 accumulation everywhere (order-insensitive).

#define F1 64
#define F2 16
#define NBKT 256  // bucket bin array size (nb = 196)
#define BSH 512   // nodes per bucket; bucket = dst>>9, local = dst&511
#define NPB 256   // scatter blocks
#define SBD 1024  // scatter block dim
#define STG 9216  // bucket region stride (mean 8192, sigma ~90)

typedef _Float16 f16x8 __attribute__((ext_vector_type(8)));
typedef _Float16 f16x4 __attribute__((ext_vector_type(4)));
typedef float f32x2 __attribute__((ext_vector_type(2)));
typedef float f32x4 __attribute__((ext_vector_type(4)));
typedef float f32x8 __attribute__((ext_vector_type(8)));

__device__ inline f32x8 shfl_xor_f32x8(f32x8 v, int off) {
  f32x8 r;
#pragma unroll
  for (int k = 0; k < 8; ++k) r[k] = __shfl_xor(v[k], off);
  return r;
}
__device__ inline f32x4 shfl_xor_f32x4(f32x4 v, int off) {
  f32x4 r;
#pragma unroll
  for (int k = 0; k < 4; ++k) r[k] = __shfl_xor(v[k], off);
  return r;
}

// accumulate 8 fp8 (e4m3) features into 4 f32x2 accs via packed cvt + packed add
__device__ inline void acc_fp8x8(f32x2* a, uint2 v) {
  a[0] += __builtin_amdgcn_cvt_pk_f32_fp8((int)v.x, false);
  a[1] += __builtin_amdgcn_cvt_pk_f32_fp8((int)v.x, true);
  a[2] += __builtin_amdgcn_cvt_pk_f32_fp8((int)v.y, false);
  a[3] += __builtin_amdgcn_cvt_pk_f32_fp8((int)v.y, true);
}

// ---- 0) weight staging + bucket cursor init ----
__global__ void k_w(const float* __restrict__ W1, const float* __restrict__ W2,
                    const float* __restrict__ b1,
                    __half* __restrict__ W1T, __half* __restrict__ W2Tp,
                    float* __restrict__ b1p, int* __restrict__ bcur, int nb) {
  int t = threadIdx.x;  // 256
  for (int i = t; i < 64 * 64; i += 256) {
    int n = i >> 6, k = i & 63;
    W1T[i] = __float2half(W1[k * 64 + n]);
  }
  // W2Tp[j*64 + p] = W2[f(p)][j], f(p) = 16*(p&3) + (p>>2)  (gemm1's permuted order)
  for (int i = t; i < 16 * 64; i += 256) {
    int j = i >> 6, p = i & 63;
    int fp = 16 * (p & 3) + (p >> 2);
    W2Tp[i] = __float2half(W2[fp * 16 + j]);
  }
  if (t < 64) b1p[t] = b1[16 * (t & 3) + (t >> 2)];
  if (t < nb) bcur[t] = t * STG;
}

// ---- 1) bucket scatter: LDS hist -> slice alloc (1 atomic/bucket/block) -> place ----
__global__ void k_bscatter(const int* __restrict__ src, const int* __restrict__ dst,
                           int* __restrict__ bcur, int* __restrict__ tmp,
                           int E, int nb, int chunk) {
  __shared__ int h[NBKT];
  __shared__ int cur[NBKT];
  int t = threadIdx.x, sb = blockIdx.x;
  int beg = sb * chunk, end = min(beg + chunk, E);
  if (t < NBKT) h[t] = 0;
  __syncthreads();
  int e;
  for (e = beg + t * 4; e + 4 <= end; e += 4 * SBD) {
    int4 d4 = *(const int4*)(dst + e);
    atomicAdd(&h[d4.x >> 9], 1);
    atomicAdd(&h[d4.y >> 9], 1);
    atomicAdd(&h[d4.z >> 9], 1);
    atomicAdd(&h[d4.w >> 9], 1);
  }
  for (; e < end; ++e) atomicAdd(&h[dst[e] >> 9], 1);
  __syncthreads();
  // allocate this block's contiguous slice in each bucket region (global index)
  if (t < nb) cur[t] = atomicAdd(&bcur[t], h[t]);
  __syncthreads();
  // place packed edges at global positions (chunk is L2-hot from pass 1)
  for (e = beg + t * 4; e + 4 <= end; e += 4 * SBD) {
    int4 d4 = *(const int4*)(dst + e);
    int4 s4 = *(const int4*)(src + e);
    int b, off;
    b = d4.x >> 9; off = atomicAdd(&cur[b], 1); tmp[off] = (s4.x << 9) | (d4.x & 511);
    b = d4.y >> 9; off = atomicAdd(&cur[b], 1); tmp[off] = (s4.y << 9) | (d4.y & 511);
    b = d4.z >> 9; off = atomicAdd(&cur[b], 1); tmp[off] = (s4.z << 9) | (d4.z & 511);
    b = d4.w >> 9; off = atomicAdd(&cur[b], 1); tmp[off] = (s4.w << 9) | (d4.w & 511);
  }
  for (; e < end; ++e) {
    int d = dst[e];
    int b = d >> 9;
    int off = atomicAdd(&cur[b], 1);
    tmp[off] = (src[e] << 9) | (d & 511);
  }
}

// ---- 2) per-bucket LDS sort -> csr + rowptr + dis (coalesced staging) ----
__global__ void k_csr(const int* __restrict__ tmp, const int* __restrict__ bcur,
                      int* __restrict__ csr, int* __restrict__ rowptr,
                      float* __restrict__ dis, int N, int nb) {
  __shared__ int stage[STG];
  __shared__ int sc[BSH];
  __shared__ int cnt[BSH];
  __shared__ int lofs[BSH];
  int b = blockIdx.x, t = threadIdx.x;  // 512 threads
  int lenb = bcur[b] - b * STG;
  // csr base of bucket b = prefix sum of bucket counts (256-wide scan)
  if (t < NBKT) sc[t] = (t < nb) ? (bcur[t] - t * STG) : 0;
  __syncthreads();
  for (int off = 1; off < NBKT; off <<= 1) {
    int a = (t < NBKT && t >= off) ? sc[t - off] : 0;
    __syncthreads();
    if (t < NBKT) sc[t] += a;
    __syncthreads();
  }
  int beg = (b == 0) ? 0 : sc[b - 1];
  __syncthreads();
  // stage bucket region into LDS: contiguous, coalesced int4
  int s0 = b * STG;
  int lim = lenb & ~3;
  for (int i = t * 4; i < lim; i += 4 * BSH)
    *(int4*)(stage + i) = *(const int4*)(tmp + s0 + i);
  {
    int r = lim + t;
    if (r < lenb) stage[r] = tmp[s0 + r];
  }
  cnt[t] = 0;
  __syncthreads();
  for (int i = t; i < lenb; i += BSH) atomicAdd(&cnt[stage[i] & (BSH - 1)], 1);
  __syncthreads();
  sc[t] = cnt[t];
  __syncthreads();
  for (int off = 1; off < BSH; off <<= 1) {
    int a = (t >= off) ? sc[t - off] : 0;
    __syncthreads();
    sc[t] += a;
    __syncthreads();
  }
  int excl = (t == 0) ? 0 : sc[t - 1];
  lofs[t] = excl;
  int n = b * BSH + t;
  if (n <= N) rowptr[n] = beg + excl;  // n==N lands on E
  if (n < N) dis[n] = rsqrtf((float)(cnt[t] + 1));
  cnt[t] = 0;  // reuse as cursor
  __syncthreads();
  for (int i = t; i < lenb; i += BSH) {
    int p = stage[i];
    int l = p & (BSH - 1);
    int off = atomicAdd(&cnt[l], 1);
    csr[beg + lofs[l] + off] = p >> 9;
  }
}

// ---- GEMM1 (MFMA): h1[n] = fp8_perm(dis[n] * (x[n] @ W1)); 64 rows/block ----
// permuted store: byte 4m+j of row n holds feature 16j+m -> one dword/thread/row
__global__ void k_gemm1(const float* __restrict__ x, const __half* __restrict__ W1T,
                        const float* __restrict__ dis, unsigned char* __restrict__ out,
                        int N) {
  int t = threadIdx.x;
  int wv = t >> 6, lane = t & 63;
  int m = lane & 15, q = lane >> 4;  // quad
  int row0 = blockIdx.x * 64 + wv * 16;
  int arow = min(row0 + m, N - 1);  // clamp for load safety
  const _Float16* wt = (const _Float16*)W1T;
  f16x8 bf[4][2];
#pragma unroll
  for (int c = 0; c < 4; ++c)
#pragma unroll
    for (int kt = 0; kt < 2; ++kt)
      bf[c][kt] = *(const f16x8*)&wt[(c * 16 + m) * 64 + kt * 32 + q * 8];
  f16x8 a[2];
#pragma unroll
  for (int kt = 0; kt < 2; ++kt) {
    const float4* xp = (const float4*)(x + (size_t)arow * 64 + kt * 32 + q * 8);
    float4 u = xp[0], v = xp[1];
    a[kt][0] = (_Float16)u.x; a[kt][1] = (_Float16)u.y;
    a[kt][2] = (_Float16)u.z; a[kt][3] = (_Float16)u.w;
    a[kt][4] = (_Float16)v.x; a[kt][5] = (_Float16)v.y;
    a[kt][6] = (_Float16)v.z; a[kt][7] = (_Float16)v.w;
  }
  f32x4 acc[4] = {};
#pragma unroll
  for (int kt = 0; kt < 2; ++kt)
#pragma unroll
    for (int c = 0; c < 4; ++c)
      acc[c] = __builtin_amdgcn_mfma_f32_16x16x32_f16(a[kt], bf[c][kt], acc[c], 0, 0, 0);
#pragma unroll
  for (int r = 0; r < 4; ++r) {
    int n = row0 + q * 4 + r;
    if (n < N) {
      float dn = dis[n];
      int d = __builtin_amdgcn_cvt_pk_fp8_f32(acc[0][r] * dn, acc[1][r] * dn, 0, false);
      d = __builtin_amdgcn_cvt_pk_fp8_f32(acc[2][r] * dn, acc[3][r] * dn, d, true);
      *(unsigned int*)(out + (size_t)n * 64 + m * 4) = (unsigned)d;
    }
  }
}

// ---- agg layer 1 + fused GEMM2: 2 nodes/wave (half=32 lanes: 4 subs x 8 fl) ----
// h1 rows are 64 B fp8 (permuted feature order, pre-scaled by dis); fp32 accumulate.
// 4 row-loads in flight per iteration (halves exposed L2 latency at deg~16).
__global__ void k_agg1f(const unsigned char* __restrict__ h, const float* __restrict__ dis,
                        const int* __restrict__ rowptr, const int* __restrict__ csr,
                        const float* __restrict__ b1p, const __half* __restrict__ W2Tp,
                        __half* __restrict__ h2, int N) {
  int gt = blockIdx.x * blockDim.x + threadIdx.x;
  int w = gt >> 6;
  int lane = gt & 63;
  int half = lane >> 5;         // node within wave
  int sub = (lane >> 3) & 3;    // 4 edge substreams per node
  int fl = lane & 7;            // feature-octet lane
  int n = w * 2 + half;
  if (n >= N) return;
  float dn = dis[n];
  float4 bu = *(const float4*)(b1p + fl * 8);
  float4 bv = *(const float4*)(b1p + fl * 8 + 4);
  const _Float16* wt = (const _Float16*)W2Tp;
  // 4 outputs per sub: j = sub*4 + i
  f16x8 wj[4];
#pragma unroll
  for (int i = 0; i < 4; ++i)
    wj[i] = *(const f16x8*)&wt[(sub * 4 + i) * 64 + fl * 8];
  f32x2 a0[4] = {}, a1[4] = {};
  if (sub == 0)  // self loop (rows pre-scaled by dis)
    acc_fp8x8(a0, *(const uint2*)&h[(size_t)n * 64 + fl * 8]);
  int beg = rowptr[n], end = rowptr[n + 1];
  int e = beg + sub;
  int s0 = (e < end) ? csr[e] : -1;
  int s1 = (e + 4 < end) ? csr[e + 4] : -1;
  int s2 = (e + 8 < end) ? csr[e + 8] : -1;
  int s3 = (e + 12 < end) ? csr[e + 12] : -1;
  while (s3 >= 0) {
    int e2 = e + 16;
    int t0 = (e2 < end) ? csr[e2] : -1;
    int t1 = (e2 + 4 < end) ? csr[e2 + 4] : -1;
    int t2 = (e2 + 8 < end) ? csr[e2 + 8] : -1;
    int t3 = (e2 + 12 < end) ? csr[e2 + 12] : -1;
    uint2 v0 = *(const uint2*)&h[(size_t)s0 * 64 + fl * 8];
    uint2 v1 = *(const uint2*)&h[(size_t)s1 * 64 + fl * 8];
    uint2 v2 = *(const uint2*)&h[(size_t)s2 * 64 + fl * 8];
    uint2 v3 = *(const uint2*)&h[(size_t)s3 * 64 + fl * 8];
    acc_fp8x8(a0, v0);
    acc_fp8x8(a1, v1);
    acc_fp8x8(a0, v2);
    acc_fp8x8(a1, v3);
    s0 = t0; s1 = t1; s2 = t2; s3 = t3; e = e2;
  }
  // tail: up to 3 remaining streams (independent loads)
  if (s0 >= 0) acc_fp8x8(a0, *(const uint2*)&h[(size_t)s0 * 64 + fl * 8]);
  if (s1 >= 0) acc_fp8x8(a1, *(const uint2*)&h[(size_t)s1 * 64 + fl * 8]);
  if (s2 >= 0) acc_fp8x8(a0, *(const uint2*)&h[(size_t)s2 * 64 + fl * 8]);
  f32x8 acc;
#pragma unroll
  for (int k = 0; k < 4; ++k) {
    f32x2 s = a0[k] + a1[k];
    acc[2 * k] = s[0];
    acc[2 * k + 1] = s[1];
  }
  // reduce across the 4 substreams (stay within 32-lane half), fp32
  acc += shfl_xor_f32x8(acc, 8);
  acc += shfl_xor_f32x8(acc, 16);
  // bias + relu in fp32
  float bb[8] = {bu.x, bu.y, bu.z, bu.w, bv.x, bv.y, bv.z, bv.w};
  float hr[8];
#pragma unroll
  for (int k = 0; k < 8; ++k)
    hr[k] = fmaxf(fmaf(dn, acc[k], bb[k]), 0.f);
  // fused gemm2 in fp32: outputs j = sub*4 .. sub*4+3
  float p[4];
#pragma unroll
  for (int i = 0; i < 4; ++i) {
    float s = 0.f;
#pragma unroll
    for (int k = 0; k < 8; ++k) s = fmaf(hr[k], (float)wj[i][k], s);
    s += __shfl_xor(s, 1);
    s += __shfl_xor(s, 2);
    s += __shfl_xor(s, 4);
    p[i] = s;
  }
  if (fl == 0) {
    f16x4 o;
#pragma unroll
    for (int i = 0; i < 4; ++i) o[i] = (_Float16)(p[i] * dn);
    *(f16x4*)((_Float16*)h2 + (size_t)n * 16 + sub * 4) = o;
  }
}

// ---- agg layer 2 + bias + log_softmax: 2 nodes/wave (8 subs x 4 fl per node) ----
// 4 row-loads in flight per iteration.
__global__ void k_agg2(const __half* __restrict__ h2, const float* __restrict__ dis,
                       const int* __restrict__ rowptr, const int* __restrict__ csr,
                       const float* __restrict__ b2, float* __restrict__ out, int N) {
  int gt = blockIdx.x * blockDim.x + threadIdx.x;
  int w = gt >> 6;
  int lane = gt & 63;
  int half = lane >> 5;
  int sub = (lane >> 2) & 7;  // 8 edge substreams per node
  int fl = lane & 3;          // feature-quad lane
  int n = w * 2 + half;
  if (n >= N) return;
  const _Float16* hp = (const _Float16*)h2;
  f32x4 acc0 = {}, acc1 = {};
  if (sub == 0)  // self loop (h2 rows pre-scaled by dis)
    acc0 = __builtin_convertvector(*(const f16x4*)&hp[(size_t)n * 16 + fl * 4], f32x4);
  int beg = rowptr[n], end = rowptr[n + 1];
  int e = beg + sub;
  int s0 = (e < end) ? csr[e] : -1;
  int s1 = (e + 8 < end) ? csr[e + 8] : -1;
  int s2 = (e + 16 < end) ? csr[e + 16] : -1;
  int s3 = (e + 24 < end) ? csr[e + 24] : -1;
  while (s3 >= 0) {
    int e2 = e + 32;
    int t0 = (e2 < end) ? csr[e2] : -1;
    int t1 = (e2 + 8 < end) ? csr[e2 + 8] : -1;
    int t2 = (e2 + 16 < end) ? csr[e2 + 16] : -1;
    int t3 = (e2 + 24 < end) ? csr[e2 + 24] : -1;
    f16x4 v0 = *(const f16x4*)&hp[(size_t)s0 * 16 + fl * 4];
    f16x4 v1 = *(const f16x4*)&hp[(size_t)s1 * 16 + fl * 4];
    f16x4 v2 = *(const f16x4*)&hp[(size_t)s2 * 16 + fl * 4];
    f16x4 v3 = *(const f16x4*)&hp[(size_t)s3 * 16 + fl * 4];
    acc0 += __builtin_convertvector(v0, f32x4);
    acc1 += __builtin_convertvector(v1, f32x4);
    acc0 += __builtin_convertvector(v2, f32x4);
    acc1 += __builtin_convertvector(v3, f32x4);
    s0 = t0; s1 = t1; s2 = t2; s3 = t3; e = e2;
  }
  if (s0 >= 0) acc0 += __builtin_convertvector(*(const f16x4*)&hp[(size_t)s0 * 16 + fl * 4], f32x4);
  if (s1 >= 0) acc1 += __builtin_convertvector(*(const f16x4*)&hp[(size_t)s1 * 16 + fl * 4], f32x4);
  if (s2 >= 0) acc0 += __builtin_convertvector(*(const f16x4*)&hp[(size_t)s2 * 16 + fl * 4], f32x4);
  f32x4 acc = acc0 + acc1;
  // reduce across 8 substreams (within half), fp32
  acc += shfl_xor_f32x4(acc, 4);
  acc += shfl_xor_f32x4(acc, 8);
  acc += shfl_xor_f32x4(acc, 16);
  if (sub == 0) {
    float dn = dis[n];
    float4 bb = *(const float4*)(b2 + fl * 4);
    float v0 = fmaf(dn, acc[0], bb.x);
    float v1 = fmaf(dn, acc[1], bb.y);
    float v2 = fmaf(dn, acc[2], bb.z);
    float v3 = fmaf(dn, acc[3], bb.w);
    float m = fmaxf(fmaxf(v0, v1), fmaxf(v2, v3));
    m = fmaxf(m, __shfl_xor(m, 1));
    m = fmaxf(m, __shfl_xor(m, 2));
    float s2 = __expf(v0 - m) + __expf(v1 - m) + __expf(v2 - m) + __expf(v3 - m);
    s2 += __shfl_xor(s2, 1);
    s2 += __shfl_xor(s2, 2);
    float ls = m + __logf(s2);
    float4 o = {v0 - ls, v1 - ls, v2 - ls, v3 - ls};
    *(float4*)(out + (size_t)n * 16 + fl * 4) = o;
  }
}

extern "C" void kernel_launch(void* const* d_in, const int* in_sizes, int n_in,
                              void* d_out, int out_size, void* d_ws, size_t ws_size,
                              hipStream_t stream) {
  const float* x = (const float*)d_in[0];
  const int* ei = (const int*)d_in[1];
  const float* W1 = (const float*)d_in[2];
  const float* b1 = (const float*)d_in[3];
  const float* W2 = (const float*)d_in[4];
  const float* b2 = (const float*)d_in[5];
  float* out = (float*)d_out;

  int N = in_sizes[0] / F1;  // 100000
  int E = in_sizes[1] / 2;   // 1600000
  const int* src = ei;
  const int* dst = ei + E;
  int nb = (N + BSH - 1) >> 9;  // 196 buckets
  int chunk = ((E + NPB - 1) / NPB + 3) & ~3;  // 6252

  char* ws = (char*)d_ws;
  size_t o_w1t = 0;                                                   // 64*64 fp16
  size_t o_w2t = o_w1t + 64 * 64 * 2;                                 // 16*64 fp16
  size_t o_b1p = (o_w2t + 16 * 64 * 2 + 255) & ~(size_t)255;          // 64 f32
  size_t o_bcur = (o_b1p + 64 * 4 + 255) & ~(size_t)255;              // NBKT int
  size_t o_dis = (o_bcur + NBKT * 4 + 255) & ~(size_t)255;            // N f32
  size_t o_rowp = (o_dis + (size_t)N * 4 + 255) & ~(size_t)255;       // N+1 int
  size_t o_tmp = (o_rowp + (size_t)(N + 1) * 4 + 255) & ~(size_t)255; // nb*STG int
  size_t o_csr = (o_tmp + (size_t)nb * STG * 4 + 255) & ~(size_t)255; // E int
  size_t o_h1 = (o_csr + (size_t)E * 4 + 255) & ~(size_t)255;         // N*64 fp8
  size_t o_h2 = (o_h1 + (size_t)N * 64 + 255) & ~(size_t)255;         // N*16 fp16

  __half* W1T = (__half*)(ws + o_w1t);
  __half* W2Tp = (__half*)(ws + o_w2t);
  float* b1p = (float*)(ws + o_b1p);
  int* bcur = (int*)(ws + o_bcur);
  float* dis = (float*)(ws + o_dis);
  int* rowptr = (int*)(ws + o_rowp);
  int* tmp = (int*)(ws + o_tmp);
  int* csr = (int*)(ws + o_csr);
  unsigned char* h1 = (unsigned char*)(ws + o_h1);
  __half* h2 = (__half*)(ws + o_h2);

  k_w<<<1, 256, 0, stream>>>(W1, W2, b1, W1T, W2Tp, b1p, bcur, nb);
  k_bscatter<<<NPB, SBD, 0, stream>>>(src, dst, bcur, tmp, E, nb, chunk);
  k_csr<<<nb, BSH, 0, stream>>>(tmp, bcur, csr, rowptr, dis, N, nb);
  int gb = (N + 63) / 64;  // 1563
  k_gemm1<<<gb, 256, 0, stream>>>(x, W1T, dis, h1, N);
  int aw = (N + 1) / 2;  // waves for 2-node-per-wave agg kernels
  k_agg1f<<<((size_t)aw * 64 + 255) / 256, 256, 0, stream>>>(h1, dis, rowptr, csr, b1p, W2Tp, h2, N);
  k_agg2<<<((size_t)aw * 64 + 255) / 256, 256, 0, stream>>>(h2, dis, rowptr, csr, b2, out, N);
}

// Round 11
// 182.925 us; speedup vs baseline: 1.3734x; 1.0959x over previous
//
#include <hip/hip_runtime.h>
#include <hip/hip_bf16.h>
#include <hip/hip_fp16.h>

// GCN 2-layer: h1 = relu(A_hat (x@W1) + b1); out = log_softmax(A_hat (h1@W2) + b2)
// R23 = R19 pipeline with gemm1 FUSED into the bucket-sort kernel (k_cg2):
// bucket block b's sort computes cnt[] = deg of exactly nodes [b*512,(b+1)*512),
// so after csr placement the same 8-wave block runs the MFMA gemm for its own 512
// rows, reading dn from LDS dnode[] (written pre-barrier; gemm doesn't touch
// stage/cnt). Deletes the serial k_gemm1 launch and overlaps gemm with the sort's
// latency phase. R22's 4-deep agg pipelines REVERTED (measured: VGPR 40->52,
// occupancy 59->36%, agg1f 44->54us -- ILP killed the TLP that hides latency);
// aggs are the proven 2-deep forms. fp32 accumulation everywhere.

#define F1 64
#define F2 16
#define NBKT 256  // bucket bin array size (nb = 196)
#define BSH 512   // nodes per bucket; bucket = dst>>9, local = dst&511
#define NPB 256   // scatter blocks
#define SBD 1024  // scatter block dim
#define STG 9216  // bucket region stride (mean 8192, sigma ~90)

typedef _Float16 f16x8 __attribute__((ext_vector_type(8)));
typedef _Float16 f16x4 __attribute__((ext_vector_type(4)));
typedef float f32x2 __attribute__((ext_vector_type(2)));
typedef float f32x4 __attribute__((ext_vector_type(4)));
typedef float f32x8 __attribute__((ext_vector_type(8)));

__device__ inline f32x8 shfl_xor_f32x8(f32x8 v, int off) {
  f32x8 r;
#pragma unroll
  for (int k = 0; k < 8; ++k) r[k] = __shfl_xor(v[k], off);
  return r;
}
__device__ inline f32x4 shfl_xor_f32x4(f32x4 v, int off) {
  f32x4 r;
#pragma unroll
  for (int k = 0; k < 4; ++k) r[k] = __shfl_xor(v[k], off);
  return r;
}

// accumulate 8 fp8 (e4m3) features into 4 f32x2 accs via packed cvt + packed add
__device__ inline void acc_fp8x8(f32x2* a, uint2 v) {
  a[0] += __builtin_amdgcn_cvt_pk_f32_fp8((int)v.x, false);
  a[1] += __builtin_amdgcn_cvt_pk_f32_fp8((int)v.x, true);
  a[2] += __builtin_amdgcn_cvt_pk_f32_fp8((int)v.y, false);
  a[3] += __builtin_amdgcn_cvt_pk_f32_fp8((int)v.y, true);
}

// ---- 0) weight staging + bucket cursor init ----
__global__ void k_w(const float* __restrict__ W1, const float* __restrict__ W2,
                    const float* __restrict__ b1,
                    __half* __restrict__ W1T, __half* __restrict__ W2Tp,
                    float* __restrict__ b1p, int* __restrict__ bcur, int nb) {
  int t = threadIdx.x;  // 256
  for (int i = t; i < 64 * 64; i += 256) {
    int n = i >> 6, k = i & 63;
    W1T[i] = __float2half(W1[k * 64 + n]);
  }
  // W2Tp[j*64 + p] = W2[f(p)][j], f(p) = 16*(p&3) + (p>>2)  (gemm1's permuted order)
  for (int i = t; i < 16 * 64; i += 256) {
    int j = i >> 6, p = i & 63;
    int fp = 16 * (p & 3) + (p >> 2);
    W2Tp[i] = __float2half(W2[fp * 16 + j]);
  }
  if (t < 64) b1p[t] = b1[16 * (t & 3) + (t >> 2)];
  if (t < nb) bcur[t] = t * STG;
}

// ---- 1) bucket scatter: LDS hist -> slice alloc (1 atomic/bucket/block) -> place ----
__global__ void k_bscatter(const int* __restrict__ src, const int* __restrict__ dst,
                           int* __restrict__ bcur, int* __restrict__ tmp,
                           int E, int nb, int chunk) {
  __shared__ int h[NBKT];
  __shared__ int cur[NBKT];
  int t = threadIdx.x, sb = blockIdx.x;
  int beg = sb * chunk, end = min(beg + chunk, E);
  if (t < NBKT) h[t] = 0;
  __syncthreads();
  int e;
  for (e = beg + t * 4; e + 4 <= end; e += 4 * SBD) {
    int4 d4 = *(const int4*)(dst + e);
    atomicAdd(&h[d4.x >> 9], 1);
    atomicAdd(&h[d4.y >> 9], 1);
    atomicAdd(&h[d4.z >> 9], 1);
    atomicAdd(&h[d4.w >> 9], 1);
  }
  for (; e < end; ++e) atomicAdd(&h[dst[e] >> 9], 1);
  __syncthreads();
  // allocate this block's contiguous slice in each bucket region (global index)
  if (t < nb) cur[t] = atomicAdd(&bcur[t], h[t]);
  __syncthreads();
  // place packed edges at global positions (chunk is L2-hot from pass 1)
  for (e = beg + t * 4; e + 4 <= end; e += 4 * SBD) {
    int4 d4 = *(const int4*)(dst + e);
    int4 s4 = *(const int4*)(src + e);
    int b, off;
    b = d4.x >> 9; off = atomicAdd(&cur[b], 1); tmp[off] = (s4.x << 9) | (d4.x & 511);
    b = d4.y >> 9; off = atomicAdd(&cur[b], 1); tmp[off] = (s4.y << 9) | (d4.y & 511);
    b = d4.z >> 9; off = atomicAdd(&cur[b], 1); tmp[off] = (s4.z << 9) | (d4.z & 511);
    b = d4.w >> 9; off = atomicAdd(&cur[b], 1); tmp[off] = (s4.w << 9) | (d4.w & 511);
  }
  for (; e < end; ++e) {
    int d = dst[e];
    int b = d >> 9;
    int off = atomicAdd(&cur[b], 1);
    tmp[off] = (src[e] << 9) | (d & 511);
  }
}

// ---- 2) FUSED per-bucket: LDS sort -> csr/rowptr/dis, then MFMA gemm1 for the
// bucket's own 512 rows (dn from LDS dnode[], filled during the sort phase).
__global__ void k_cg2(const int* __restrict__ tmp, const int* __restrict__ bcur,
                      int* __restrict__ csr, int* __restrict__ rowptr,
                      float* __restrict__ dis,
                      const float* __restrict__ x, const __half* __restrict__ W1T,
                      unsigned char* __restrict__ h1, int N, int nb) {
  __shared__ int stage[STG];
  __shared__ int sc[BSH];
  __shared__ int cnt[BSH];
  __shared__ int lofs[BSH];
  __shared__ float dnode[BSH];
  int b = blockIdx.x, t = threadIdx.x;  // 512 threads
  int lenb = bcur[b] - b * STG;
  // csr base of bucket b = prefix sum of bucket counts (256-wide scan)
  if (t < NBKT) sc[t] = (t < nb) ? (bcur[t] - t * STG) : 0;
  __syncthreads();
  for (int off = 1; off < NBKT; off <<= 1) {
    int a = (t < NBKT && t >= off) ? sc[t - off] : 0;
    __syncthreads();
    if (t < NBKT) sc[t] += a;
    __syncthreads();
  }
  int beg = (b == 0) ? 0 : sc[b - 1];
  __syncthreads();
  // stage bucket region into LDS: contiguous, coalesced int4
  int s0 = b * STG;
  int lim = lenb & ~3;
  for (int i = t * 4; i < lim; i += 4 * BSH)
    *(int4*)(stage + i) = *(const int4*)(tmp + s0 + i);
  {
    int r = lim + t;
    if (r < lenb) stage[r] = tmp[s0 + r];
  }
  cnt[t] = 0;
  __syncthreads();
  for (int i = t; i < lenb; i += BSH) atomicAdd(&cnt[stage[i] & (BSH - 1)], 1);
  __syncthreads();
  sc[t] = cnt[t];
  __syncthreads();
  for (int off = 1; off < BSH; off <<= 1) {
    int a = (t >= off) ? sc[t - off] : 0;
    __syncthreads();
    sc[t] += a;
    __syncthreads();
  }
  int excl = (t == 0) ? 0 : sc[t - 1];
  lofs[t] = excl;
  int n = b * BSH + t;
  float dn_t = rsqrtf((float)(cnt[t] + 1));
  dnode[t] = dn_t;  // visible to all after the next barrier
  if (n <= N) rowptr[n] = beg + excl;  // n==N lands on E
  if (n < N) dis[n] = dn_t;
  cnt[t] = 0;  // reuse as cursor
  __syncthreads();
  for (int i = t; i < lenb; i += BSH) {
    int p = stage[i];
    int l = p & (BSH - 1);
    int off = atomicAdd(&cnt[l], 1);
    csr[beg + lofs[l] + off] = p >> 9;
  }
  // ---- gemm1 role: this bucket's 512 rows; 8 waves x 4 iterations x 16 rows ----
  // (no barrier needed: gemm touches only x/W1T/dnode; dnode writes are pre-barrier)
  int wv = t >> 6, lane = t & 63;
  int m = lane & 15, q = lane >> 4;  // quad
  const _Float16* wt = (const _Float16*)W1T;
  f16x8 bf[4][2];
#pragma unroll
  for (int c = 0; c < 4; ++c)
#pragma unroll
    for (int kt = 0; kt < 2; ++kt)
      bf[c][kt] = *(const f16x8*)&wt[(c * 16 + m) * 64 + kt * 32 + q * 8];
#pragma unroll
  for (int it = 0; it < 4; ++it) {
    int lrow0 = wv * 64 + it * 16;      // local row in bucket
    int row0 = b * BSH + lrow0;         // global row
    int arow = min(row0 + m, N - 1);    // clamp for load safety
    f16x8 a[2];
#pragma unroll
    for (int kt = 0; kt < 2; ++kt) {
      const float4* xp = (const float4*)(x + (size_t)arow * 64 + kt * 32 + q * 8);
      float4 u = xp[0], v = xp[1];
      a[kt][0] = (_Float16)u.x; a[kt][1] = (_Float16)u.y;
      a[kt][2] = (_Float16)u.z; a[kt][3] = (_Float16)u.w;
      a[kt][4] = (_Float16)v.x; a[kt][5] = (_Float16)v.y;
      a[kt][6] = (_Float16)v.z; a[kt][7] = (_Float16)v.w;
    }
    f32x4 acc[4] = {};
#pragma unroll
    for (int kt = 0; kt < 2; ++kt)
#pragma unroll
      for (int c = 0; c < 4; ++c)
        acc[c] = __builtin_amdgcn_mfma_f32_16x16x32_f16(a[kt], bf[c][kt], acc[c], 0, 0, 0);
#pragma unroll
    for (int r = 0; r < 4; ++r) {
      int lr = lrow0 + q * 4 + r;
      int nn = b * BSH + lr;
      if (nn < N) {
        float dn = dnode[lr];
        int d = __builtin_amdgcn_cvt_pk_fp8_f32(acc[0][r] * dn, acc[1][r] * dn, 0, false);
        d = __builtin_amdgcn_cvt_pk_fp8_f32(acc[2][r] * dn, acc[3][r] * dn, d, true);
        *(unsigned int*)(h1 + (size_t)nn * 64 + m * 4) = (unsigned)d;
      }
    }
  }
}

// ---- agg layer 1 + fused GEMM2: 2 nodes/wave (half=32 lanes: 4 subs x 8 fl) ----
// h1 rows are 64 B fp8 (permuted feature order, pre-scaled by dis); fp32 accumulate.
// 2-deep stream pipeline (proven best: deeper kills occupancy, R22).
__global__ void k_agg1f(const unsigned char* __restrict__ h, const float* __restrict__ dis,
                        const int* __restrict__ rowptr, const int* __restrict__ csr,
                        const float* __restrict__ b1p, const __half* __restrict__ W2Tp,
                        __half* __restrict__ h2, int N) {
  int gt = blockIdx.x * blockDim.x + threadIdx.x;
  int w = gt >> 6;
  int lane = gt & 63;
  int half = lane >> 5;         // node within wave
  int sub = (lane >> 3) & 3;    // 4 edge substreams per node
  int fl = lane & 7;            // feature-octet lane
  int n = w * 2 + half;
  if (n >= N) return;
  float dn = dis[n];
  float4 bu = *(const float4*)(b1p + fl * 8);
  float4 bv = *(const float4*)(b1p + fl * 8 + 4);
  const _Float16* wt = (const _Float16*)W2Tp;
  // 4 outputs per sub: j = sub*4 + i
  f16x8 wj[4];
#pragma unroll
  for (int i = 0; i < 4; ++i)
    wj[i] = *(const f16x8*)&wt[(sub * 4 + i) * 64 + fl * 8];
  f32x2 a0[4] = {}, a1[4] = {};
  if (sub == 0)  // self loop (rows pre-scaled by dis)
    acc_fp8x8(a0, *(const uint2*)&h[(size_t)n * 64 + fl * 8]);
  int beg = rowptr[n], end = rowptr[n + 1];
  int e = beg + sub;
  int sA = (e < end) ? csr[e] : -1;
  int sB = (e + 4 < end) ? csr[e + 4] : -1;
  while (sB >= 0) {
    int e2 = e + 8;
    int sC = (e2 < end) ? csr[e2] : -1;
    int sD = (e2 + 4 < end) ? csr[e2 + 4] : -1;
    uint2 v0 = *(const uint2*)&h[(size_t)sA * 64 + fl * 8];
    uint2 v1 = *(const uint2*)&h[(size_t)sB * 64 + fl * 8];
    acc_fp8x8(a0, v0);
    acc_fp8x8(a1, v1);
    sA = sC; sB = sD; e = e2;
  }
  if (sA >= 0)
    acc_fp8x8(a0, *(const uint2*)&h[(size_t)sA * 64 + fl * 8]);
  f32x8 acc;
#pragma unroll
  for (int k = 0; k < 4; ++k) {
    f32x2 s = a0[k] + a1[k];
    acc[2 * k] = s[0];
    acc[2 * k + 1] = s[1];
  }
  // reduce across the 4 substreams (stay within 32-lane half), fp32
  acc += shfl_xor_f32x8(acc, 8);
  acc += shfl_xor_f32x8(acc, 16);
  // bias + relu in fp32
  float bb[8] = {bu.x, bu.y, bu.z, bu.w, bv.x, bv.y, bv.z, bv.w};
  float hr[8];
#pragma unroll
  for (int k = 0; k < 8; ++k)
    hr[k] = fmaxf(fmaf(dn, acc[k], bb[k]), 0.f);
  // fused gemm2 in fp32: outputs j = sub*4 .. sub*4+3
  float p[4];
#pragma unroll
  for (int i = 0; i < 4; ++i) {
    float s = 0.f;
#pragma unroll
    for (int k = 0; k < 8; ++k) s = fmaf(hr[k], (float)wj[i][k], s);
    s += __shfl_xor(s, 1);
    s += __shfl_xor(s, 2);
    s += __shfl_xor(s, 4);
    p[i] = s;
  }
  if (fl == 0) {
    f16x4 o;
#pragma unroll
    for (int i = 0; i < 4; ++i) o[i] = (_Float16)(p[i] * dn);
    *(f16x4*)((_Float16*)h2 + (size_t)n * 16 + sub * 4) = o;
  }
}

// ---- agg layer 2 + bias + log_softmax: 2 nodes/wave (8 subs x 4 fl per node) ----
__global__ void k_agg2(const __half* __restrict__ h2, const float* __restrict__ dis,
                       const int* __restrict__ rowptr, const int* __restrict__ csr,
                       const float* __restrict__ b2, float* __restrict__ out, int N) {
  int gt = blockIdx.x * blockDim.x + threadIdx.x;
  int w = gt >> 6;
  int lane = gt & 63;
  int half = lane >> 5;
  int sub = (lane >> 2) & 7;  // 8 edge substreams per node
  int fl = lane & 3;          // feature-quad lane
  int n = w * 2 + half;
  if (n >= N) return;
  const _Float16* hp = (const _Float16*)h2;
  f32x4 acc0 = {}, acc1 = {};
  if (sub == 0)  // self loop (h2 rows pre-scaled by dis)
    acc0 = __builtin_convertvector(*(const f16x4*)&hp[(size_t)n * 16 + fl * 4], f32x4);
  int beg = rowptr[n], end = rowptr[n + 1];
  int e = beg + sub;
  int sA = (e < end) ? csr[e] : -1;
  int sB = (e + 8 < end) ? csr[e + 8] : -1;
  while (sB >= 0) {
    int e2 = e + 16;
    int sC = (e2 < end) ? csr[e2] : -1;
    int sD = (e2 + 8 < end) ? csr[e2 + 8] : -1;
    f16x4 v0 = *(const f16x4*)&hp[(size_t)sA * 16 + fl * 4];
    f16x4 v1 = *(const f16x4*)&hp[(size_t)sB * 16 + fl * 4];
    acc0 += __builtin_convertvector(v0, f32x4);
    acc1 += __builtin_convertvector(v1, f32x4);
    sA = sC; sB = sD; e = e2;
  }
  if (sA >= 0)
    acc0 += __builtin_convertvector(*(const f16x4*)&hp[(size_t)sA * 16 + fl * 4], f32x4);
  f32x4 acc = acc0 + acc1;
  // reduce across 8 substreams (within half), fp32
  acc += shfl_xor_f32x4(acc, 4);
  acc += shfl_xor_f32x4(acc, 8);
  acc += shfl_xor_f32x4(acc, 16);
  if (sub == 0) {
    float dn = dis[n];
    float4 bb = *(const float4*)(b2 + fl * 4);
    float v0 = fmaf(dn, acc[0], bb.x);
    float v1 = fmaf(dn, acc[1], bb.y);
    float v2 = fmaf(dn, acc[2], bb.z);
    float v3 = fmaf(dn, acc[3], bb.w);
    float m = fmaxf(fmaxf(v0, v1), fmaxf(v2, v3));
    m = fmaxf(m, __shfl_xor(m, 1));
    m = fmaxf(m, __shfl_xor(m, 2));
    float s2 = __expf(v0 - m) + __expf(v1 - m) + __expf(v2 - m) + __expf(v3 - m);
    s2 += __shfl_xor(s2, 1);
    s2 += __shfl_xor(s2, 2);
    float ls = m + __logf(s2);
    float4 o = {v0 - ls, v1 - ls, v2 - ls, v3 - ls};
    *(float4*)(out + (size_t)n * 16 + fl * 4) = o;
  }
}

extern "C" void kernel_launch(void* const* d_in, const int* in_sizes, int n_in,
                              void* d_out, int out_size, void* d_ws, size_t ws_size,
                              hipStream_t stream) {
  const float* x = (const float*)d_in[0];
  const int* ei = (const int*)d_in[1];
  const float* W1 = (const float*)d_in[2];
  const float* b1 = (const float*)d_in[3];
  const float* W2 = (const float*)d_in[4];
  const float* b2 = (const float*)d_in[5];
  float* out = (float*)d_out;

  int N = in_sizes[0] / F1;  // 100000
  int E = in_sizes[1] / 2;   // 1600000
  const int* src = ei;
  const int* dst = ei + E;
  int nb = (N + BSH - 1) >> 9;  // 196 buckets
  int chunk = ((E + NPB - 1) / NPB + 3) & ~3;  // 6252

  char* ws = (char*)d_ws;
  size_t o_w1t = 0;                                                   // 64*64 fp16
  size_t o_w2t = o_w1t + 64 * 64 * 2;                                 // 16*64 fp16
  size_t o_b1p = (o_w2t + 16 * 64 * 2 + 255) & ~(size_t)255;          // 64 f32
  size_t o_bcur = (o_b1p + 64 * 4 + 255) & ~(size_t)255;              // NBKT int
  size_t o_dis = (o_bcur + NBKT * 4 + 255) & ~(size_t)255;            // N f32
  size_t o_rowp = (o_dis + (size_t)N * 4 + 255) & ~(size_t)255;       // N+1 int
  size_t o_tmp = (o_rowp + (size_t)(N + 1) * 4 + 255) & ~(size_t)255; // nb*STG int
  size_t o_csr = (o_tmp + (size_t)nb * STG * 4 + 255) & ~(size_t)255; // E int
  size_t o_h1 = (o_csr + (size_t)E * 4 + 255) & ~(size_t)255;         // N*64 fp8
  size_t o_h2 = (o_h1 + (size_t)N * 64 + 255) & ~(size_t)255;         // N*16 fp16

  __half* W1T = (__half*)(ws + o_w1t);
  __half* W2Tp = (__half*)(ws + o_w2t);
  float* b1p = (float*)(ws + o_b1p);
  int* bcur = (int*)(ws + o_bcur);
  float* dis = (float*)(ws + o_dis);
  int* rowptr = (int*)(ws + o_rowp);
  int* tmp = (int*)(ws + o_tmp);
  int* csr = (int*)(ws + o_csr);
  unsigned char* h1 = (unsigned char*)(ws + o_h1);
  __half* h2 = (__half*)(ws + o_h2);

  k_w<<<1, 256, 0, stream>>>(W1, W2, b1, W1T, W2Tp, b1p, bcur, nb);
  k_bscatter<<<NPB, SBD, 0, stream>>>(src, dst, bcur, tmp, E, nb, chunk);
  k_cg2<<<nb, BSH, 0, stream>>>(tmp, bcur, csr, rowptr, dis, x, W1T, h1, N, nb);
  int aw = (N + 1) / 2;  // waves for 2-node-per-wave agg kernels
  k_agg1f<<<((size_t)aw * 64 + 255) / 256, 256, 0, stream>>>(h1, dis, rowptr, csr, b1p, W2Tp, h2, N);
  k_agg2<<<((size_t)aw * 64 + 255) / 256, 256, 0, stream>>>(h2, dis, rowptr, csr, b2, out, N);
}